// Round 2
// baseline (8387.378 us; speedup 1.0000x reference)
//
#include <hip/hip_runtime.h>
#include <math.h>

#define N_NODES 50000
#define N_EDGES 400000
#define CH      256
#define NNZ     800000

__device__ __forceinline__ float sigmoidf_(float x) {
    return 1.0f / (1.0f + __expf(-x));
}

// ---------------------------------------------------------------------------
// Small utility fills (avoid hipMemsetAsync entirely — fills are plain kernels)
// ---------------------------------------------------------------------------
__global__ __launch_bounds__(256) void fill_i32(int* __restrict__ p, int val, int n)
{
    int stride = gridDim.x * 256;
    for (int i = blockIdx.x * 256 + threadIdx.x; i < n; i += stride) p[i] = val;
}

__global__ __launch_bounds__(256) void fill_f32(float* __restrict__ p, float val, int n)
{
    int stride = gridDim.x * 256;
    for (int i = blockIdx.x * 256 + threadIdx.x; i < n; i += stride) p[i] = val;
}

// ---------------------------------------------------------------------------
// Group inc entries by edge id via atomic linked list: head[edge] -> entry chain
// ---------------------------------------------------------------------------
__global__ __launch_bounds__(256) void build_list(
    const int* __restrict__ key, int* __restrict__ head, int* __restrict__ nxt, int n)
{
    int i = blockIdx.x * 256 + threadIdx.x;
    if (i >= n) return;
    nxt[i] = atomicExch(&head[key[i]], i);
}

// ---------------------------------------------------------------------------
// Fused edge branch: for each edge e (one 64-lane wave):
//   D_e = sum_{entries i with inc_cols[i]==e} vals[i] * B[inc_rows[i]]   (gather)
//   F[inc_rows[i]] += vals[i] * sigmoid(D_e)                             (scatter)
// Edge features never touch memory (registers only) — kills the 409.6 MB buffer.
// ---------------------------------------------------------------------------
__global__ __launch_bounds__(256) void edge_fused(
    const int* __restrict__ head, const int* __restrict__ nxt,
    const int* __restrict__ node, const float* __restrict__ vals,
    const float* __restrict__ B, float* __restrict__ F, int n_edges)
{
    int e    = (int)((blockIdx.x * 256u + threadIdx.x) >> 6);
    int lane = threadIdx.x & 63;
    if (e >= n_edges) return;

    float4 acc = make_float4(0.f, 0.f, 0.f, 0.f);
    for (int p = head[e]; p >= 0; p = nxt[p]) {
        int   n = node[p];
        float v = vals[p];
        float4 b = *(const float4*)(B + (size_t)n * CH + lane * 4);
        acc.x = fmaf(v, b.x, acc.x);
        acc.y = fmaf(v, b.y, acc.y);
        acc.z = fmaf(v, b.z, acc.z);
        acc.w = fmaf(v, b.w, acc.w);
    }
    acc.x = sigmoidf_(acc.x);
    acc.y = sigmoidf_(acc.y);
    acc.z = sigmoidf_(acc.z);
    acc.w = sigmoidf_(acc.w);
    for (int p = head[e]; p >= 0; p = nxt[p]) {
        int   n = node[p];
        float v = vals[p];
        float* o = F + (size_t)n * CH + lane * 4;
        atomicAdd(o + 0, v * acc.x);
        atomicAdd(o + 1, v * acc.y);
        atomicAdd(o + 2, v * acc.z);
        atomicAdd(o + 3, v * acc.w);
    }
}

// ---------------------------------------------------------------------------
// COO scatter-SpMM: O[dst[e]] += vals[e] * (sig ? sigmoid(S[src[e]]) : S[src[e]])
// one 64-lane wave per nnz, float4 per lane, fp32 atomics
// ---------------------------------------------------------------------------
__global__ __launch_bounds__(256) void scatter_spmm(
    const int* __restrict__ dst, const int* __restrict__ src,
    const float* __restrict__ vals, const float* __restrict__ S,
    float* __restrict__ O, int nnz, int sig)
{
    int gw   = (int)((blockIdx.x * 256u + threadIdx.x) >> 6);
    int lane = threadIdx.x & 63;
    if (gw >= nnz) return;
    int d = dst[gw];
    int s = src[gw];
    float v = vals[gw];

    float4 x4 = *(const float4*)(S + (size_t)s * CH + lane * 4);
    if (sig) {
        x4.x = sigmoidf_(x4.x); x4.y = sigmoidf_(x4.y);
        x4.z = sigmoidf_(x4.z); x4.w = sigmoidf_(x4.w);
    }
    float* o = O + (size_t)d * CH + lane * 4;
    atomicAdd(o + 0, v * x4.x);
    atomicAdd(o + 1, v * x4.y);
    atomicAdd(o + 2, v * x4.z);
    atomicAdd(o + 3, v * x4.w);
}

// ---------------------------------------------------------------------------
// GEMM: Y[M,256] = A0 @ W0 (+ A1 @ W1 if A1 != null), optional sigmoid epilogue
// 64x64 block tile, 16x16 threads, 4x4 microtile, BK=16, fp32 (no fp32 MFMA)
// ---------------------------------------------------------------------------
#define BK  16
#define LDT 68

__global__ __launch_bounds__(256, 2) void gemm64(
    const float* __restrict__ A0, const float* __restrict__ W0,
    const float* __restrict__ A1, const float* __restrict__ W1,
    float* __restrict__ Y, int M, int do_sigmoid)
{
    __shared__ float At[BK][LDT];   // [k][row]
    __shared__ float Wt[BK][LDT];   // [k][col]

    const int tid  = threadIdx.x;
    const int tx   = tid & 15;
    const int ty   = tid >> 4;
    const int row0 = blockIdx.x * 64;
    const int col0 = blockIdx.y * 64;

    float acc[4][4];
#pragma unroll
    for (int i = 0; i < 4; i++)
#pragma unroll
        for (int j = 0; j < 4; j++) acc[i][j] = 0.f;

    const int r_st  = tid >> 2;
    const int q_st  = tid & 3;
    const int kk_st = tid >> 4;
    const int c_st  = (tid & 15) * 4;

    for (int pass = 0; pass < 2; ++pass) {
        const float* Ap = pass ? A1 : A0;
        const float* Wp = pass ? W1 : W0;
        if (Ap == nullptr) break;

        for (int k0 = 0; k0 < 256; k0 += BK) {
            __syncthreads();
            float4 av = make_float4(0.f, 0.f, 0.f, 0.f);
            int grow = row0 + r_st;
            if (grow < M)
                av = *(const float4*)(Ap + (size_t)grow * CH + k0 + q_st * 4);
            At[q_st * 4 + 0][r_st] = av.x;
            At[q_st * 4 + 1][r_st] = av.y;
            At[q_st * 4 + 2][r_st] = av.z;
            At[q_st * 4 + 3][r_st] = av.w;
            float4 wv = *(const float4*)(Wp + (size_t)(k0 + kk_st) * CH + col0 + c_st);
            *(float4*)&Wt[kk_st][c_st] = wv;
            __syncthreads();

#pragma unroll
            for (int kk = 0; kk < BK; ++kk) {
                float4 a4 = *(const float4*)&At[kk][ty * 4];
                float4 b4 = *(const float4*)&Wt[kk][tx * 4];
                float a[4] = {a4.x, a4.y, a4.z, a4.w};
                float b[4] = {b4.x, b4.y, b4.z, b4.w};
#pragma unroll
                for (int i = 0; i < 4; i++)
#pragma unroll
                    for (int j = 0; j < 4; j++)
                        acc[i][j] = fmaf(a[i], b[j], acc[i][j]);
            }
        }
    }

#pragma unroll
    for (int i = 0; i < 4; i++) {
        int grow = row0 + ty * 4 + i;
        if (grow < M) {
            float4 o;
            o.x = acc[i][0]; o.y = acc[i][1]; o.z = acc[i][2]; o.w = acc[i][3];
            if (do_sigmoid) {
                o.x = sigmoidf_(o.x); o.y = sigmoidf_(o.y);
                o.z = sigmoidf_(o.z); o.w = sigmoidf_(o.w);
            }
            *(float4*)(Y + (size_t)grow * CH + col0 + tx * 4) = o;
        }
    }
}

// ---------------------------------------------------------------------------
extern "C" void kernel_launch(void* const* d_in, const int* in_sizes, int n_in,
                              void* d_out, int out_size, void* d_ws, size_t ws_size,
                              hipStream_t stream)
{
    const float* x        = (const float*)d_in[0];
    const int*   adj_rows = (const int*)  d_in[1];
    const int*   adj_cols = (const int*)  d_in[2];
    const float* adj_vals = (const float*)d_in[3];
    const int*   inc_rows = (const int*)  d_in[4];
    const int*   inc_cols = (const int*)  d_in[5];
    const float* inc_vals = (const float*)d_in[6];
    const float* W00      = (const float*)d_in[7];
    const float* W01      = (const float*)d_in[8];
    const float* W10      = (const float*)d_in[9];
    const float* W11      = (const float*)d_in[10];

    const size_t SZ_N = (size_t)N_NODES * CH * sizeof(float);   // 51.2 MB

    // Workspace layout (total 107.2 MB):
    //   slot0: B = x@W01, then A = x@W00, then E = spmm_adj(sigmoid(C))
    //   slot1: F = fused edge-branch output
    //   head:  400k int (inc grouped by edge), next: 800k int
    char*  ws   = (char*)d_ws;
    float* slot0 = (float*)(ws);
    float* F     = (float*)(ws + SZ_N);
    int*   head  = (int*)  (ws + 2 * SZ_N);
    int*   nxt   = (int*)  (ws + 2 * SZ_N + (size_t)N_EDGES * sizeof(int));
    float* C     = (float*)d_out;   // nodes_l1 (pre-sigmoid; dead before final GEMM)

    dim3 gemm_grid((N_NODES + 63) / 64, 4);
    const int scat_blocks = (NNZ * 64) / 256;      // 200000
    const int edge_blocks = (N_EDGES * 64) / 256;  // 100000
    const int NCH = N_NODES * CH;

    // 0) group inc entries by edge id (linked list; no scan needed, deg_avg = 2)
    fill_i32<<<1024, 256, 0, stream>>>(head, -1, N_EDGES);
    build_list<<<(NNZ + 255) / 256, 256, 0, stream>>>(inc_cols, head, nxt, NNZ);

    // 1) B = x @ W01
    gemm64<<<gemm_grid, 256, 0, stream>>>(x, W01, nullptr, nullptr, slot0, N_NODES, 0);

    // 2) F[n] += v * sigmoid(D_e), D_e computed in registers (no edge buffer)
    fill_f32<<<2048, 256, 0, stream>>>(F, 0.f, NCH);
    edge_fused<<<edge_blocks, 256, 0, stream>>>(head, nxt, inc_rows, inc_vals,
                                                slot0, F, N_EDGES);

    // 3) A = x @ W00  (slot0 reused; B dead)
    gemm64<<<gemm_grid, 256, 0, stream>>>(x, W00, nullptr, nullptr, slot0, N_NODES, 0);

    // 4) C = spmm_adj(A)  (pre-sigmoid, lives in d_out)
    fill_f32<<<2048, 256, 0, stream>>>(C, 0.f, NCH);
    scatter_spmm<<<scat_blocks, 256, 0, stream>>>(adj_rows, adj_cols, adj_vals,
                                                  slot0, C, NNZ, 0);

    // 5) E = spmm_adj(sigmoid(C))  (sigmoid applied on gather; slot0 reused, A dead)
    fill_f32<<<2048, 256, 0, stream>>>(slot0, 0.f, NCH);
    scatter_spmm<<<scat_blocks, 256, 0, stream>>>(adj_rows, adj_cols, adj_vals,
                                                  C, slot0, NNZ, 1);

    // 6) out = sigmoid(E @ W10 + F @ W11)   (GEMMs commuted past the SpMMs:
    //    saves the 400k-row GEMM — 52.4 of the reference's 72.4 GFLOP)
    gemm64<<<gemm_grid, 256, 0, stream>>>(slot0, W10, F, W11, (float*)d_out, N_NODES, 1);
}

// Round 3
// 1252.157 us; speedup vs baseline: 6.6983x; 6.6983x over previous
//
#include <hip/hip_runtime.h>
#include <math.h>

#define N_NODES 50000
#define N_EDGES 400000
#define CH      256
#define NNZ     800000

__device__ __forceinline__ float sigmoidf_(float x) {
    return 1.0f / (1.0f + __expf(-x));
}

// ---------------------------------------------------------------------------
__global__ __launch_bounds__(256) void fill_i32(int* __restrict__ p, int val, int n)
{
    int stride = gridDim.x * 256;
    for (int i = blockIdx.x * 256 + threadIdx.x; i < n; i += stride) p[i] = val;
}

// Group entries by key via atomic linked list: head[key] -> chain of entry ids
__global__ __launch_bounds__(256) void build_list(
    const int* __restrict__ key, int* __restrict__ head, int* __restrict__ nxt, int n)
{
    int i = blockIdx.x * 256 + threadIdx.x;
    if (i >= n) return;
    nxt[i] = atomicExch(&head[key[i]], i);
}

// ---------------------------------------------------------------------------
// Gather-form SpMM (NO atomics): one 64-lane wave per output row r.
//   O[r] = (sig ? sigmoid : id)( sum_{p in list(r)} vals[p] * S[col[p]] )
// ---------------------------------------------------------------------------
__global__ __launch_bounds__(256) void gather_spmm(
    const int* __restrict__ head, const int* __restrict__ nxt,
    const int* __restrict__ col, const float* __restrict__ vals,
    const float* __restrict__ S, float* __restrict__ O, int n_rows, int sig)
{
    int r    = (int)((blockIdx.x * 256u + threadIdx.x) >> 6);
    int lane = threadIdx.x & 63;
    if (r >= n_rows) return;

    float4 acc = make_float4(0.f, 0.f, 0.f, 0.f);
    for (int p = head[r]; p >= 0; p = nxt[p]) {
        int   c = col[p];
        float v = vals[p];
        float4 s4 = *(const float4*)(S + (size_t)c * CH + lane * 4);
        acc.x = fmaf(v, s4.x, acc.x);
        acc.y = fmaf(v, s4.y, acc.y);
        acc.z = fmaf(v, s4.z, acc.z);
        acc.w = fmaf(v, s4.w, acc.w);
    }
    if (sig) {
        acc.x = sigmoidf_(acc.x); acc.y = sigmoidf_(acc.y);
        acc.z = sigmoidf_(acc.z); acc.w = sigmoidf_(acc.w);
    }
    *(float4*)(O + (size_t)r * CH + lane * 4) = acc;
}

// ---------------------------------------------------------------------------
// Edge branch, full gather form (NO atomics, NO edge buffer): one wave per node.
//   F[n] = sum_{p in listN(n)} vals[p] * sigmoid( D_{edge(p)} )
//   D_e  = sum_{q in listE(e)} vals[q] * B[node(q)]      (recomputed in regs)
// Redundant D recompute = sum_e deg(e)^2 ~ 2.4M row reads of IC-resident B.
// ---------------------------------------------------------------------------
__global__ __launch_bounds__(256) void edge_gather_node(
    const int* __restrict__ headN, const int* __restrict__ nxtN,
    const int* __restrict__ entry_edge,   // inc_cols: entry -> edge id
    const int* __restrict__ headE, const int* __restrict__ nxtE,
    const int* __restrict__ entry_node,   // inc_rows: entry -> node id
    const float* __restrict__ vals,
    const float* __restrict__ B, float* __restrict__ F, int n_nodes)
{
    int n    = (int)((blockIdx.x * 256u + threadIdx.x) >> 6);
    int lane = threadIdx.x & 63;
    if (n >= n_nodes) return;

    float4 acc = make_float4(0.f, 0.f, 0.f, 0.f);
    for (int p = headN[n]; p >= 0; p = nxtN[p]) {
        int   e = entry_edge[p];
        float v = vals[p];
        float4 d = make_float4(0.f, 0.f, 0.f, 0.f);
        for (int q = headE[e]; q >= 0; q = nxtE[q]) {
            int   m = entry_node[q];
            float u = vals[q];
            float4 b = *(const float4*)(B + (size_t)m * CH + lane * 4);
            d.x = fmaf(u, b.x, d.x);
            d.y = fmaf(u, b.y, d.y);
            d.z = fmaf(u, b.z, d.z);
            d.w = fmaf(u, b.w, d.w);
        }
        acc.x = fmaf(v, sigmoidf_(d.x), acc.x);
        acc.y = fmaf(v, sigmoidf_(d.y), acc.y);
        acc.z = fmaf(v, sigmoidf_(d.z), acc.z);
        acc.w = fmaf(v, sigmoidf_(d.w), acc.w);
    }
    *(float4*)(F + (size_t)n * CH + lane * 4) = acc;
}

// ---------------------------------------------------------------------------
// GEMM: Y[M,256] = A0 @ W0 (+ A1 @ W1 if A1 != null), optional sigmoid epilogue
// 64x64 block tile, 16x16 threads, 4x4 microtile, BK=16, fp32 (no fp32 MFMA)
// ---------------------------------------------------------------------------
#define BK  16
#define LDT 68

__global__ __launch_bounds__(256, 2) void gemm64(
    const float* __restrict__ A0, const float* __restrict__ W0,
    const float* __restrict__ A1, const float* __restrict__ W1,
    float* __restrict__ Y, int M, int do_sigmoid)
{
    __shared__ float At[BK][LDT];   // [k][row]
    __shared__ float Wt[BK][LDT];   // [k][col]

    const int tid  = threadIdx.x;
    const int tx   = tid & 15;
    const int ty   = tid >> 4;
    const int row0 = blockIdx.x * 64;
    const int col0 = blockIdx.y * 64;

    float acc[4][4];
#pragma unroll
    for (int i = 0; i < 4; i++)
#pragma unroll
        for (int j = 0; j < 4; j++) acc[i][j] = 0.f;

    const int r_st  = tid >> 2;
    const int q_st  = tid & 3;
    const int kk_st = tid >> 4;
    const int c_st  = (tid & 15) * 4;

    for (int pass = 0; pass < 2; ++pass) {
        const float* Ap = pass ? A1 : A0;
        const float* Wp = pass ? W1 : W0;
        if (Ap == nullptr) break;

        for (int k0 = 0; k0 < 256; k0 += BK) {
            __syncthreads();
            float4 av = make_float4(0.f, 0.f, 0.f, 0.f);
            int grow = row0 + r_st;
            if (grow < M)
                av = *(const float4*)(Ap + (size_t)grow * CH + k0 + q_st * 4);
            At[q_st * 4 + 0][r_st] = av.x;
            At[q_st * 4 + 1][r_st] = av.y;
            At[q_st * 4 + 2][r_st] = av.z;
            At[q_st * 4 + 3][r_st] = av.w;
            float4 wv = *(const float4*)(Wp + (size_t)(k0 + kk_st) * CH + col0 + c_st);
            *(float4*)&Wt[kk_st][c_st] = wv;
            __syncthreads();

#pragma unroll
            for (int kk = 0; kk < BK; ++kk) {
                float4 a4 = *(const float4*)&At[kk][ty * 4];
                float4 b4 = *(const float4*)&Wt[kk][tx * 4];
                float a[4] = {a4.x, a4.y, a4.z, a4.w};
                float b[4] = {b4.x, b4.y, b4.z, b4.w};
#pragma unroll
                for (int i = 0; i < 4; i++)
#pragma unroll
                    for (int j = 0; j < 4; j++)
                        acc[i][j] = fmaf(a[i], b[j], acc[i][j]);
            }
        }
    }

#pragma unroll
    for (int i = 0; i < 4; i++) {
        int grow = row0 + ty * 4 + i;
        if (grow < M) {
            float4 o;
            o.x = acc[i][0]; o.y = acc[i][1]; o.z = acc[i][2]; o.w = acc[i][3];
            if (do_sigmoid) {
                o.x = sigmoidf_(o.x); o.y = sigmoidf_(o.y);
                o.z = sigmoidf_(o.z); o.w = sigmoidf_(o.w);
            }
            *(float4*)(Y + (size_t)grow * CH + col0 + tx * 4) = o;
        }
    }
}

// ---------------------------------------------------------------------------
extern "C" void kernel_launch(void* const* d_in, const int* in_sizes, int n_in,
                              void* d_out, int out_size, void* d_ws, size_t ws_size,
                              hipStream_t stream)
{
    const float* x        = (const float*)d_in[0];
    const int*   adj_rows = (const int*)  d_in[1];
    const int*   adj_cols = (const int*)  d_in[2];
    const float* adj_vals = (const float*)d_in[3];
    const int*   inc_rows = (const int*)  d_in[4];
    const int*   inc_cols = (const int*)  d_in[5];
    const float* inc_vals = (const float*)d_in[6];
    const float* W00      = (const float*)d_in[7];
    const float* W01      = (const float*)d_in[8];
    const float* W10      = (const float*)d_in[9];
    const float* W11      = (const float*)d_in[10];

    const size_t SZ_N = (size_t)N_NODES * CH * sizeof(float);   // 51.2 MB

    // Workspace (~114 MB): two feature slots + linked lists
    char*  ws    = (char*)d_ws;
    float* slot0 = (float*)(ws);            // B, then A, then E
    float* F     = (float*)(ws + SZ_N);     // edge-branch node output
    int*   head_a = (int*)(ws + 2 * SZ_N);  // adj grouped by dst row   [N_NODES]
    int*   head_e = head_a + N_NODES;       // inc grouped by edge      [N_EDGES]
    int*   head_n = head_e + N_EDGES;       // inc grouped by node      [N_NODES]
    int*   nxt_a  = head_n + N_NODES;       // [NNZ]
    int*   nxt_e  = nxt_a + NNZ;            // [NNZ]
    int*   nxt_n  = nxt_e + NNZ;            // [NNZ]
    float* C      = (float*)d_out;          // nodes_l1 (sigmoided); dead before final GEMM

    dim3 gemm_grid((N_NODES + 63) / 64, 4);
    const int row_blocks  = (N_NODES * 64 + 255) / 256;  // 12500 (wave per node)
    const int list_blocks = (NNZ + 255) / 256;

    // 0) build the three linked-list groupings (heads are contiguous: one fill)
    fill_i32<<<1024, 256, 0, stream>>>(head_a, -1, N_NODES + N_EDGES + N_NODES);
    build_list<<<list_blocks, 256, 0, stream>>>(adj_rows, head_a, nxt_a, NNZ);
    build_list<<<list_blocks, 256, 0, stream>>>(inc_cols, head_e, nxt_e, NNZ);
    build_list<<<list_blocks, 256, 0, stream>>>(inc_rows, head_n, nxt_n, NNZ);

    // 1) B = x @ W01
    gemm64<<<gemm_grid, 256, 0, stream>>>(x, W01, nullptr, nullptr, slot0, N_NODES, 0);

    // 2) F[n] = sum_p v_p * sigmoid(D_e)  — D recomputed in registers, no atomics
    edge_gather_node<<<row_blocks, 256, 0, stream>>>(head_n, nxt_n, inc_cols,
                                                     head_e, nxt_e, inc_rows,
                                                     inc_vals, slot0, F, N_NODES);

    // 3) A = x @ W00  (slot0 reused, B dead)
    gemm64<<<gemm_grid, 256, 0, stream>>>(x, W00, nullptr, nullptr, slot0, N_NODES, 0);

    // 4) C = sigmoid(gather_adj(A))  — sigmoid fused into store
    gather_spmm<<<row_blocks, 256, 0, stream>>>(head_a, nxt_a, adj_cols, adj_vals,
                                                slot0, C, N_NODES, 1);

    // 5) E = gather_adj(C)  (slot0 reused, A dead)
    gather_spmm<<<row_blocks, 256, 0, stream>>>(head_a, nxt_a, adj_cols, adj_vals,
                                                C, slot0, N_NODES, 0);

    // 6) out = sigmoid(E @ W10 + F @ W11)
    gemm64<<<gemm_grid, 256, 0, stream>>>(slot0, W10, F, W11, (float*)d_out, N_NODES, 1);
}

// Round 4
// 1161.395 us; speedup vs baseline: 7.2218x; 1.0781x over previous
//
#include <hip/hip_runtime.h>
#include <math.h>

#define N_NODES 50000
#define N_EDGES 400000
#define CH      256
#define NNZ     800000

typedef short s16x8 __attribute__((ext_vector_type(8)));
typedef float f32x4 __attribute__((ext_vector_type(4)));

__device__ __forceinline__ float sigmoidf_(float x) {
    return 1.0f / (1.0f + __expf(-x));
}
__device__ __forceinline__ unsigned short f2bf(float f) {
    unsigned u = __float_as_uint(f);
    u = (u + 0x7FFFu + ((u >> 16) & 1u)) >> 16;   // RNE
    return (unsigned short)u;
}
__device__ __forceinline__ float bf2f(unsigned short h) {
    return __uint_as_float((unsigned)h << 16);
}

// ---------------------------------------------------------------------------
__global__ __launch_bounds__(256) void fill_i32(int* __restrict__ p, int val, int n)
{
    int stride = gridDim.x * 256;
    for (int i = blockIdx.x * 256 + threadIdx.x; i < n; i += stride) p[i] = val;
}

__global__ __launch_bounds__(256) void build_list(
    const int* __restrict__ key, int* __restrict__ head, int* __restrict__ nxt, int n)
{
    int i = blockIdx.x * 256 + threadIdx.x;
    if (i >= n) return;
    nxt[i] = atomicExch(&head[key[i]], i);
}

// W[k][n] fp32 -> Wt[n][k] bf16 (transposed, so MFMA B-frags are contiguous)
__global__ __launch_bounds__(256) void cvt_w_transpose(
    const float* __restrict__ W0, const float* __restrict__ W1,
    unsigned short* __restrict__ T0, unsigned short* __restrict__ T1)
{
    int n = blockIdx.x, k = threadIdx.x;
    T0[n * 256 + k] = f2bf(W0[k * 256 + n]);
    T1[n * 256 + k] = f2bf(W1[k * 256 + n]);
}

// ---------------------------------------------------------------------------
// MFMA GEMM: Y[M][256] (bf16) = X[M][256] (fp32, converted inline) @ W (via Wt[n][k] bf16)
// 4 waves/block, wave = 16 rows x 256 cols = 16 tiles of 16x16, K-step 32.
// Frag layout (gfx950 16x16x32): A/B: m|n=lane&15, k=(lane>>4)*8+i ; D: col=lane&15,
// row=(lane>>4)*4+reg  [m89-verified].
// ---------------------------------------------------------------------------
__global__ __launch_bounds__(256) void mfma_gemm(
    const float* __restrict__ X, const unsigned short* __restrict__ Wt,
    unsigned short* __restrict__ Y, int M)
{
    const int wv = threadIdx.x >> 6, lane = threadIdx.x & 63;
    const int row0 = blockIdx.x * 64 + wv * 16;
    const int r = lane & 15, g = lane >> 4;

    f32x4 acc[16];
#pragma unroll
    for (int t = 0; t < 16; t++) acc[t] = (f32x4){0.f, 0.f, 0.f, 0.f};

    int arow = row0 + r; if (arow >= M) arow = M - 1;   // clamp (dup read, store guarded)

#pragma unroll
    for (int k0 = 0; k0 < 256; k0 += 32) {
        const float* xp = X + (size_t)arow * CH + k0 + g * 8;
        float4 f0 = *(const float4*)(xp);
        float4 f1 = *(const float4*)(xp + 4);
        s16x8 a;
        a[0] = f2bf(f0.x); a[1] = f2bf(f0.y); a[2] = f2bf(f0.z); a[3] = f2bf(f0.w);
        a[4] = f2bf(f1.x); a[5] = f2bf(f1.y); a[6] = f2bf(f1.z); a[7] = f2bf(f1.w);
#pragma unroll
        for (int t = 0; t < 16; t++) {
            s16x8 b = *(const s16x8*)(Wt + (size_t)(t * 16 + r) * CH + k0 + g * 8);
            acc[t] = __builtin_amdgcn_mfma_f32_16x16x32_bf16(a, b, acc[t], 0, 0, 0);
        }
    }

    const int drow0 = row0 + g * 4;
#pragma unroll
    for (int t = 0; t < 16; t++) {
        int col = t * 16 + r;
#pragma unroll
        for (int j = 0; j < 4; j++) {
            int dr = drow0 + j;
            if (dr < M) Y[(size_t)dr * CH + col] = f2bf(acc[t][j]);
        }
    }
}

// ---------------------------------------------------------------------------
// Gather SpMM, bf16 source rows (8 B/lane): O[r] = act( sum vals[p]*S[col[p]] )
// out_bf: store bf16 (ushort4) else fp32 (float4)
// ---------------------------------------------------------------------------
__global__ __launch_bounds__(256) void gather_bf(
    const int* __restrict__ head, const int* __restrict__ nxt,
    const int* __restrict__ col, const float* __restrict__ vals,
    const unsigned short* __restrict__ S, void* __restrict__ O,
    int n_rows, int sig, int out_bf)
{
    int r    = (int)((blockIdx.x * 256u + threadIdx.x) >> 6);
    int lane = threadIdx.x & 63;
    if (r >= n_rows) return;

    float4 acc = make_float4(0.f, 0.f, 0.f, 0.f);
    for (int p = head[r]; p >= 0; p = nxt[p]) {
        int   c = col[p];
        float v = vals[p];
        ushort4 s = *(const ushort4*)(S + (size_t)c * CH + lane * 4);
        acc.x = fmaf(v, bf2f(s.x), acc.x);
        acc.y = fmaf(v, bf2f(s.y), acc.y);
        acc.z = fmaf(v, bf2f(s.z), acc.z);
        acc.w = fmaf(v, bf2f(s.w), acc.w);
    }
    if (sig) {
        acc.x = sigmoidf_(acc.x); acc.y = sigmoidf_(acc.y);
        acc.z = sigmoidf_(acc.z); acc.w = sigmoidf_(acc.w);
    }
    if (out_bf) {
        ushort4 o; o.x = f2bf(acc.x); o.y = f2bf(acc.y); o.z = f2bf(acc.z); o.w = f2bf(acc.w);
        *(ushort4*)((unsigned short*)O + (size_t)r * CH + lane * 4) = o;
    } else {
        *(float4*)((float*)O + (size_t)r * CH + lane * 4) = acc;
    }
}

// ---------------------------------------------------------------------------
// Edge branch (no atomics, no edge buffer), bf16 B rows:
//   F[n] = sum_{p in listN(n)} vals[p] * sigmoid( D_{edge(p)} ),
//   D_e recomputed in registers from listE(e).
// ---------------------------------------------------------------------------
__global__ __launch_bounds__(256) void edge_gather_node(
    const int* __restrict__ headN, const int* __restrict__ nxtN,
    const int* __restrict__ entry_edge,
    const int* __restrict__ headE, const int* __restrict__ nxtE,
    const int* __restrict__ entry_node,
    const float* __restrict__ vals,
    const unsigned short* __restrict__ B, float* __restrict__ F, int n_nodes)
{
    int n    = (int)((blockIdx.x * 256u + threadIdx.x) >> 6);
    int lane = threadIdx.x & 63;
    if (n >= n_nodes) return;

    float4 acc = make_float4(0.f, 0.f, 0.f, 0.f);
    for (int p = headN[n]; p >= 0; p = nxtN[p]) {
        int   e = entry_edge[p];
        float v = vals[p];
        float4 d = make_float4(0.f, 0.f, 0.f, 0.f);
        for (int q = headE[e]; q >= 0; q = nxtE[q]) {
            int   m = entry_node[q];
            float u = vals[q];
            ushort4 b = *(const ushort4*)(B + (size_t)m * CH + lane * 4);
            d.x = fmaf(u, bf2f(b.x), d.x);
            d.y = fmaf(u, bf2f(b.y), d.y);
            d.z = fmaf(u, bf2f(b.z), d.z);
            d.w = fmaf(u, bf2f(b.w), d.w);
        }
        acc.x = fmaf(v, sigmoidf_(d.x), acc.x);
        acc.y = fmaf(v, sigmoidf_(d.y), acc.y);
        acc.z = fmaf(v, sigmoidf_(d.z), acc.z);
        acc.w = fmaf(v, sigmoidf_(d.w), acc.w);
    }
    *(float4*)(F + (size_t)n * CH + lane * 4) = acc;
}

// ---------------------------------------------------------------------------
// Final GEMM, fp32, IN-PLACE on d_out (E == Y): out = sigmoid(E@W10 + F@W11).
// One block per 64-row stripe computing ALL 256 cols (acc 64 f32/thread), so a
// block writes only its own rows after reading only its own rows -> E=d_out safe.
// ---------------------------------------------------------------------------
#define FBK 16

__global__ __launch_bounds__(256, 2) void final_gemm(
    const float* __restrict__ E, const float* __restrict__ F,
    const float* __restrict__ W10, const float* __restrict__ W11,
    float* __restrict__ Y, int M)
{
    __shared__ float At[FBK][68];
    __shared__ float Wt[FBK][260];

    const int tid = threadIdx.x;
    const int tx = tid & 15, ty = tid >> 4;
    const int row0 = blockIdx.x * 64;

    float acc[4][16];
#pragma unroll
    for (int i = 0; i < 4; i++)
#pragma unroll
        for (int j = 0; j < 16; j++) acc[i][j] = 0.f;

    const int r_st  = tid >> 2;        // A staging row 0..63
    const int q_st  = tid & 3;         // A staging k-quad
    const int kk_st = tid >> 4;        // W staging k row 0..15
    const int c_st  = (tid & 15) * 16; // W staging col base

    for (int pass = 0; pass < 2; ++pass) {
        const float* Ap = pass ? F : E;
        const float* Wp = pass ? W11 : W10;

        for (int k0 = 0; k0 < 256; k0 += FBK) {
            __syncthreads();
            float4 av = make_float4(0.f, 0.f, 0.f, 0.f);
            int grow = row0 + r_st;
            if (grow < M)
                av = *(const float4*)(Ap + (size_t)grow * CH + k0 + q_st * 4);
            At[q_st * 4 + 0][r_st] = av.x;
            At[q_st * 4 + 1][r_st] = av.y;
            At[q_st * 4 + 2][r_st] = av.z;
            At[q_st * 4 + 3][r_st] = av.w;
#pragma unroll
            for (int q = 0; q < 4; q++) {
                float4 wv = *(const float4*)(Wp + (size_t)(k0 + kk_st) * CH + c_st + q * 4);
                *(float4*)&Wt[kk_st][c_st + q * 4] = wv;
            }
            __syncthreads();

#pragma unroll
            for (int kk = 0; kk < FBK; ++kk) {
                float4 a4 = *(const float4*)&At[kk][ty * 4];
                float a[4] = {a4.x, a4.y, a4.z, a4.w};
#pragma unroll
                for (int j = 0; j < 16; j++) {
                    float w = Wt[kk][tx + 16 * j];
#pragma unroll
                    for (int i = 0; i < 4; i++)
                        acc[i][j] = fmaf(a[i], w, acc[i][j]);
                }
            }
        }
    }

#pragma unroll
    for (int i = 0; i < 4; i++) {
        int grow = row0 + ty * 4 + i;
        if (grow < M) {
#pragma unroll
            for (int j = 0; j < 16; j++)
                Y[(size_t)grow * CH + tx + 16 * j] = sigmoidf_(acc[i][j]);
        }
    }
}

// ---------------------------------------------------------------------------
extern "C" void kernel_launch(void* const* d_in, const int* in_sizes, int n_in,
                              void* d_out, int out_size, void* d_ws, size_t ws_size,
                              hipStream_t stream)
{
    const float* x        = (const float*)d_in[0];
    const int*   adj_rows = (const int*)  d_in[1];
    const int*   adj_cols = (const int*)  d_in[2];
    const float* adj_vals = (const float*)d_in[3];
    const int*   inc_rows = (const int*)  d_in[4];
    const int*   inc_cols = (const int*)  d_in[5];
    const float* inc_vals = (const float*)d_in[6];
    const float* W00      = (const float*)d_in[7];
    const float* W01      = (const float*)d_in[8];
    const float* W10      = (const float*)d_in[9];
    const float* W11      = (const float*)d_in[10];

    // Workspace layout (114.26 MB total — matches the proven-safe footprint):
    const size_t SZ_BF = (size_t)N_NODES * CH * 2;   // 25.6 MB
    const size_t SZ_F32 = (size_t)N_NODES * CH * 4;  // 51.2 MB
    char* ws = (char*)d_ws;
    unsigned short* AB_bf = (unsigned short*)(ws);                    // B, then A
    unsigned short* C_bf  = (unsigned short*)(ws + SZ_BF);            // nodes_l1 (bf16)
    float*          F     = (float*)(ws + 2 * SZ_BF);                 // edge-branch out
    int*   head_a = (int*)(ws + 2 * SZ_BF + SZ_F32);
    int*   head_e = head_a + N_NODES;
    int*   head_n = head_e + N_EDGES;
    int*   nxt_a  = head_n + N_NODES;
    int*   nxt_e  = nxt_a + NNZ;
    int*   nxt_n  = nxt_e + NNZ;
    unsigned short* Wt00 = (unsigned short*)((char*)(nxt_n + NNZ));
    unsigned short* Wt01 = Wt00 + CH * CH;
    float* E = (float*)d_out;   // E lives in d_out; final_gemm is in-place-safe

    const int gemm_blocks = (N_NODES + 63) / 64;         // 782
    const int row_blocks  = (N_NODES * 64 + 255) / 256;  // 12500
    const int list_blocks = (NNZ + 255) / 256;

    // 0) linked-list groupings + weight convert/transpose
    fill_i32<<<1024, 256, 0, stream>>>(head_a, -1, N_NODES + N_EDGES + N_NODES);
    build_list<<<list_blocks, 256, 0, stream>>>(adj_rows, head_a, nxt_a, NNZ);
    build_list<<<list_blocks, 256, 0, stream>>>(inc_cols, head_e, nxt_e, NNZ);
    build_list<<<list_blocks, 256, 0, stream>>>(inc_rows, head_n, nxt_n, NNZ);
    cvt_w_transpose<<<256, 256, 0, stream>>>(W00, W01, Wt00, Wt01);

    // 1) B = x @ W01  (bf16, MFMA)
    mfma_gemm<<<gemm_blocks, 256, 0, stream>>>(x, Wt01, AB_bf, N_NODES);

    // 2) F[n] = sum v * sigmoid(D_e)   (D in registers; reads bf16 B)
    edge_gather_node<<<row_blocks, 256, 0, stream>>>(head_n, nxt_n, inc_cols,
                                                     head_e, nxt_e, inc_rows,
                                                     inc_vals, AB_bf, F, N_NODES);

    // 3) A = x @ W00  (bf16, MFMA; overwrites B — dead)
    mfma_gemm<<<gemm_blocks, 256, 0, stream>>>(x, Wt00, AB_bf, N_NODES);

    // 4) C = sigmoid(gather_adj(A))  -> bf16
    gather_bf<<<row_blocks, 256, 0, stream>>>(head_a, nxt_a, adj_cols, adj_vals,
                                              AB_bf, C_bf, N_NODES, 1, 1);

    // 5) E = gather_adj(C)  -> fp32 in d_out
    gather_bf<<<row_blocks, 256, 0, stream>>>(head_a, nxt_a, adj_cols, adj_vals,
                                              C_bf, E, N_NODES, 0, 0);

    // 6) out = sigmoid(E @ W10 + F @ W11)  (fp32, in-place on d_out)
    final_gemm<<<gemm_blocks, 256, 0, stream>>>(E, F, W10, W11, (float*)d_out, N_NODES);
}

// Round 5
// 1131.948 us; speedup vs baseline: 7.4097x; 1.0260x over previous
//
#include <hip/hip_runtime.h>
#include <math.h>

#define N_NODES 50000
#define N_EDGES 400000
#define CH      256
#define NNZ     800000

typedef short s16x8 __attribute__((ext_vector_type(8)));
typedef float f32x4 __attribute__((ext_vector_type(4)));

__device__ __forceinline__ float sigmoidf_(float x) {
    return 1.0f / (1.0f + __expf(-x));
}
__device__ __forceinline__ unsigned short f2bf(float f) {
    unsigned u = __float_as_uint(f);
    u = (u + 0x7FFFu + ((u >> 16) & 1u)) >> 16;   // RNE
    return (unsigned short)u;
}
__device__ __forceinline__ float bf2f(unsigned short h) {
    return __uint_as_float((unsigned)h << 16);
}

// ---------------------------------------------------------------------------
__global__ __launch_bounds__(256) void fill_i32(int* __restrict__ p, int val, int n)
{
    int stride = gridDim.x * 256;
    for (int i = blockIdx.x * 256 + threadIdx.x; i < n; i += stride) p[i] = val;
}

__global__ __launch_bounds__(256) void build_list(
    const int* __restrict__ key, int* __restrict__ head, int* __restrict__ nxt, int n)
{
    int i = blockIdx.x * 256 + threadIdx.x;
    if (i >= n) return;
    nxt[i] = atomicExch(&head[key[i]], i);
}

// Convert linked list -> packed CSR (no scan): sd[k] = base | (deg<<20).
// base < 2^20 (nnz<=800k), deg < 4096 (Poisson(16) max ~50).
__global__ __launch_bounds__(256) void pack_csr(
    const int* __restrict__ head, const int* __restrict__ nxt,
    const int* __restrict__ other, const float* __restrict__ vals_src,
    int* __restrict__ sd, int* __restrict__ col_out, float* __restrict__ val_out,
    int* __restrict__ cursor, int n_keys)
{
    int k = blockIdx.x * 256 + threadIdx.x;
    if (k >= n_keys) return;
    int deg = 0;
    for (int p = head[k]; p >= 0; p = nxt[p]) deg++;
    int base = deg ? atomicAdd(cursor, deg) : 0;
    sd[k] = base | (deg << 20);
    int i = base;
    for (int p = head[k]; p >= 0; p = nxt[p]) {
        col_out[i] = other[p];
        val_out[i] = vals_src[p];
        i++;
    }
}

// W[k][n] fp32 -> Wt[n][k] bf16 (transposed, so MFMA B-frags are contiguous)
__global__ __launch_bounds__(256) void cvt_w_transpose(
    const float* __restrict__ W0, const float* __restrict__ W1,
    unsigned short* __restrict__ T0, unsigned short* __restrict__ T1)
{
    int n = blockIdx.x, k = threadIdx.x;
    T0[n * 256 + k] = f2bf(W0[k * 256 + n]);
    T1[n * 256 + k] = f2bf(W1[k * 256 + n]);
}

// ---------------------------------------------------------------------------
// MFMA GEMM: Y[M][256] (bf16) = X[M][256] (fp32) @ W (via Wt[n][k] bf16)
// ---------------------------------------------------------------------------
__global__ __launch_bounds__(256) void mfma_gemm(
    const float* __restrict__ X, const unsigned short* __restrict__ Wt,
    unsigned short* __restrict__ Y, int M)
{
    const int wv = threadIdx.x >> 6, lane = threadIdx.x & 63;
    const int row0 = blockIdx.x * 64 + wv * 16;
    const int r = lane & 15, g = lane >> 4;

    f32x4 acc[16];
#pragma unroll
    for (int t = 0; t < 16; t++) acc[t] = (f32x4){0.f, 0.f, 0.f, 0.f};

    int arow = row0 + r; if (arow >= M) arow = M - 1;

#pragma unroll
    for (int k0 = 0; k0 < 256; k0 += 32) {
        const float* xp = X + (size_t)arow * CH + k0 + g * 8;
        float4 f0 = *(const float4*)(xp);
        float4 f1 = *(const float4*)(xp + 4);
        s16x8 a;
        a[0] = f2bf(f0.x); a[1] = f2bf(f0.y); a[2] = f2bf(f0.z); a[3] = f2bf(f0.w);
        a[4] = f2bf(f1.x); a[5] = f2bf(f1.y); a[6] = f2bf(f1.z); a[7] = f2bf(f1.w);
#pragma unroll
        for (int t = 0; t < 16; t++) {
            s16x8 b = *(const s16x8*)(Wt + (size_t)(t * 16 + r) * CH + k0 + g * 8);
            acc[t] = __builtin_amdgcn_mfma_f32_16x16x32_bf16(a, b, acc[t], 0, 0, 0);
        }
    }

    const int drow0 = row0 + g * 4;
#pragma unroll
    for (int t = 0; t < 16; t++) {
        int col = t * 16 + r;
#pragma unroll
        for (int j = 0; j < 4; j++) {
            int dr = drow0 + j;
            if (dr < M) Y[(size_t)dr * CH + col] = f2bf(acc[t][j]);
        }
    }
}

// ---------------------------------------------------------------------------
// CSR gather SpMM (bf16 rows): O[r] = act( sum_i val[i]*S[col[i]] ), unroll x4
// ---------------------------------------------------------------------------
__global__ __launch_bounds__(256) void gather_csr(
    const int* __restrict__ sd, const int* __restrict__ col,
    const float* __restrict__ val, const unsigned short* __restrict__ S,
    void* __restrict__ O, int n_rows, int sig, int out_bf)
{
    int r    = (int)((blockIdx.x * 256u + threadIdx.x) >> 6);
    int lane = threadIdx.x & 63;
    if (r >= n_rows) return;
    r = __builtin_amdgcn_readfirstlane(r);   // wave-uniform -> scalar index loads

    unsigned sdv = (unsigned)sd[r];
    int base = (int)(sdv & 0xFFFFFu), deg = (int)(sdv >> 20);
    const int lo = lane * 4;

    float4 acc = make_float4(0.f, 0.f, 0.f, 0.f);
    int i = 0;
    for (; i + 4 <= deg; i += 4) {
        int c0 = col[base+i],   c1 = col[base+i+1];
        int c2 = col[base+i+2], c3 = col[base+i+3];
        float v0 = val[base+i],   v1 = val[base+i+1];
        float v2 = val[base+i+2], v3 = val[base+i+3];
        ushort4 s0 = *(const ushort4*)(S + (size_t)c0 * CH + lo);
        ushort4 s1 = *(const ushort4*)(S + (size_t)c1 * CH + lo);
        ushort4 s2 = *(const ushort4*)(S + (size_t)c2 * CH + lo);
        ushort4 s3 = *(const ushort4*)(S + (size_t)c3 * CH + lo);
        acc.x += v0*bf2f(s0.x) + v1*bf2f(s1.x) + v2*bf2f(s2.x) + v3*bf2f(s3.x);
        acc.y += v0*bf2f(s0.y) + v1*bf2f(s1.y) + v2*bf2f(s2.y) + v3*bf2f(s3.y);
        acc.z += v0*bf2f(s0.z) + v1*bf2f(s1.z) + v2*bf2f(s2.z) + v3*bf2f(s3.z);
        acc.w += v0*bf2f(s0.w) + v1*bf2f(s1.w) + v2*bf2f(s2.w) + v3*bf2f(s3.w);
    }
    for (; i < deg; i++) {
        int   c = col[base+i];
        float v = val[base+i];
        ushort4 s = *(const ushort4*)(S + (size_t)c * CH + lo);
        acc.x = fmaf(v, bf2f(s.x), acc.x);
        acc.y = fmaf(v, bf2f(s.y), acc.y);
        acc.z = fmaf(v, bf2f(s.z), acc.z);
        acc.w = fmaf(v, bf2f(s.w), acc.w);
    }
    if (sig) {
        acc.x = sigmoidf_(acc.x); acc.y = sigmoidf_(acc.y);
        acc.z = sigmoidf_(acc.z); acc.w = sigmoidf_(acc.w);
    }
    if (out_bf) {
        ushort4 o; o.x = f2bf(acc.x); o.y = f2bf(acc.y); o.z = f2bf(acc.z); o.w = f2bf(acc.w);
        *(ushort4*)((unsigned short*)O + (size_t)r * CH + lo) = o;
    } else {
        *(float4*)((float*)O + (size_t)r * CH + lo) = acc;
    }
}

// ---------------------------------------------------------------------------
// Edge branch via double CSR (no atomics, no edge buffer):
//   F[n] = sum_{i in csrN(n)} v_i * sigmoid( D_{e_i} ),
//   D_e  = sum_{j in csrE(e)} u_j * B[m_j]     (recomputed in registers)
// ---------------------------------------------------------------------------
__global__ __launch_bounds__(256) void edge_gather_csr(
    const int* __restrict__ sd_n, const int* __restrict__ edge_n,
    const float* __restrict__ val_n,
    const int* __restrict__ sd_e, const int* __restrict__ node_e,
    const float* __restrict__ val_e,
    const unsigned short* __restrict__ B, float* __restrict__ F, int n_nodes)
{
    int n    = (int)((blockIdx.x * 256u + threadIdx.x) >> 6);
    int lane = threadIdx.x & 63;
    if (n >= n_nodes) return;
    n = __builtin_amdgcn_readfirstlane(n);

    unsigned sdn = (unsigned)sd_n[n];
    int baseN = (int)(sdn & 0xFFFFFu), degN = (int)(sdn >> 20);
    const int lo = lane * 4;

    float4 acc = make_float4(0.f, 0.f, 0.f, 0.f);
    for (int i = 0; i < degN; i++) {
        int   e = edge_n[baseN + i];
        float v = val_n[baseN + i];
        unsigned sde = (unsigned)sd_e[e];
        int baseE = (int)(sde & 0xFFFFFu), degE = (int)(sde >> 20);

        float4 d = make_float4(0.f, 0.f, 0.f, 0.f);
        int j = 0;
        for (; j + 2 <= degE; j += 2) {
            int   m0 = node_e[baseE+j],   m1 = node_e[baseE+j+1];
            float u0 = val_e[baseE+j],    u1 = val_e[baseE+j+1];
            ushort4 b0 = *(const ushort4*)(B + (size_t)m0 * CH + lo);
            ushort4 b1 = *(const ushort4*)(B + (size_t)m1 * CH + lo);
            d.x += u0*bf2f(b0.x) + u1*bf2f(b1.x);
            d.y += u0*bf2f(b0.y) + u1*bf2f(b1.y);
            d.z += u0*bf2f(b0.z) + u1*bf2f(b1.z);
            d.w += u0*bf2f(b0.w) + u1*bf2f(b1.w);
        }
        for (; j < degE; j++) {
            int   m = node_e[baseE+j];
            float u = val_e[baseE+j];
            ushort4 b = *(const ushort4*)(B + (size_t)m * CH + lo);
            d.x = fmaf(u, bf2f(b.x), d.x);
            d.y = fmaf(u, bf2f(b.y), d.y);
            d.z = fmaf(u, bf2f(b.z), d.z);
            d.w = fmaf(u, bf2f(b.w), d.w);
        }
        acc.x = fmaf(v, sigmoidf_(d.x), acc.x);
        acc.y = fmaf(v, sigmoidf_(d.y), acc.y);
        acc.z = fmaf(v, sigmoidf_(d.z), acc.z);
        acc.w = fmaf(v, sigmoidf_(d.w), acc.w);
    }
    *(float4*)(F + (size_t)n * CH + lo) = acc;
}

// ---------------------------------------------------------------------------
// Final GEMM, fp32, IN-PLACE on d_out: out = sigmoid(E@W10 + F@W11).
// ---------------------------------------------------------------------------
#define FBK 16

__global__ __launch_bounds__(256, 2) void final_gemm(
    const float* __restrict__ E, const float* __restrict__ F,
    const float* __restrict__ W10, const float* __restrict__ W11,
    float* __restrict__ Y, int M)
{
    __shared__ float At[FBK][68];
    __shared__ float Wt[FBK][260];

    const int tid = threadIdx.x;
    const int tx = tid & 15, ty = tid >> 4;
    const int row0 = blockIdx.x * 64;

    float acc[4][16];
#pragma unroll
    for (int i = 0; i < 4; i++)
#pragma unroll
        for (int j = 0; j < 16; j++) acc[i][j] = 0.f;

    const int r_st  = tid >> 2;
    const int q_st  = tid & 3;
    const int kk_st = tid >> 4;
    const int c_st  = (tid & 15) * 16;

    for (int pass = 0; pass < 2; ++pass) {
        const float* Ap = pass ? F : E;
        const float* Wp = pass ? W11 : W10;

        for (int k0 = 0; k0 < 256; k0 += FBK) {
            __syncthreads();
            float4 av = make_float4(0.f, 0.f, 0.f, 0.f);
            int grow = row0 + r_st;
            if (grow < M)
                av = *(const float4*)(Ap + (size_t)grow * CH + k0 + q_st * 4);
            At[q_st * 4 + 0][r_st] = av.x;
            At[q_st * 4 + 1][r_st] = av.y;
            At[q_st * 4 + 2][r_st] = av.z;
            At[q_st * 4 + 3][r_st] = av.w;
#pragma unroll
            for (int q = 0; q < 4; q++) {
                float4 wv = *(const float4*)(Wp + (size_t)(k0 + kk_st) * CH + c_st + q * 4);
                *(float4*)&Wt[kk_st][c_st + q * 4] = wv;
            }
            __syncthreads();

#pragma unroll
            for (int kk = 0; kk < FBK; ++kk) {
                float4 a4 = *(const float4*)&At[kk][ty * 4];
                float a[4] = {a4.x, a4.y, a4.z, a4.w};
#pragma unroll
                for (int j = 0; j < 16; j++) {
                    float w = Wt[kk][tx + 16 * j];
#pragma unroll
                    for (int i = 0; i < 4; i++)
                        acc[i][j] = fmaf(a[i], w, acc[i][j]);
                }
            }
        }
    }

#pragma unroll
    for (int i = 0; i < 4; i++) {
        int grow = row0 + ty * 4 + i;
        if (grow < M) {
#pragma unroll
            for (int j = 0; j < 16; j++)
                Y[(size_t)grow * CH + tx + 16 * j] = sigmoidf_(acc[i][j]);
        }
    }
}

// ---------------------------------------------------------------------------
extern "C" void kernel_launch(void* const* d_in, const int* in_sizes, int n_in,
                              void* d_out, int out_size, void* d_ws, size_t ws_size,
                              hipStream_t stream)
{
    const float* x        = (const float*)d_in[0];
    const int*   adj_rows = (const int*)  d_in[1];
    const int*   adj_cols = (const int*)  d_in[2];
    const float* adj_vals = (const float*)d_in[3];
    const int*   inc_rows = (const int*)  d_in[4];
    const int*   inc_cols = (const int*)  d_in[5];
    const float* inc_vals = (const float*)d_in[6];
    const float* W00      = (const float*)d_in[7];
    const float* W01      = (const float*)d_in[8];
    const float* W10      = (const float*)d_in[9];
    const float* W11      = (const float*)d_in[10];

    // -------- workspace layout (109.9 MB total; proven-safe < 114.26 MB) ----
    const size_t SZ_AB = (size_t)N_NODES * CH * 2;    // 25.6 MB
    const size_t SZ_F  = (size_t)N_NODES * CH * 4;    // 51.2 MB
    char* ws = (char*)d_ws;
    size_t off = 0;
    unsigned short* AB_bf = (unsigned short*)(ws + off); off += SZ_AB;
    float*          F     = (float*)(ws + off);          off += SZ_F;
    // adj CSR (live through steps 8-9)
    int*   sd_a  = (int*)(ws + off);  off += (size_t)N_NODES * 4;
    int*   col_a = (int*)(ws + off);  off += (size_t)NNZ * 4;
    float* val_a = (float*)(ws + off); off += (size_t)NNZ * 4;
    int*   cursors = (int*)(ws + off); off += 256;      // 3 cursors, padded
    unsigned short* Wt00 = (unsigned short*)(ws + off); off += (size_t)CH * CH * 2;
    unsigned short* Wt01 = (unsigned short*)(ws + off); off += (size_t)CH * CH * 2;
    // scratch region: lists + inc CSRs (all dead after edge_gather_csr);
    // C_bf overlays it afterwards.
    char* scratch = ws + off;
    int*   head_a = (int*)(scratch);
    int*   head_e = head_a + N_NODES;
    int*   head_n = head_e + N_EDGES;
    int*   nxt_a  = head_n + N_NODES;      // reused for all three lists? no: 3 arrays
    int*   nxt_e  = nxt_a + NNZ;
    int*   nxt_n  = nxt_e + NNZ;
    int*   sd_n   = nxt_n + NNZ;
    int*   edge_n = sd_n + N_NODES;
    float* val_n  = (float*)(edge_n + NNZ);
    int*   sd_e   = (int*)(val_n + NNZ);
    int*   node_e = sd_e + N_EDGES;
    float* val_e  = (float*)(node_e + NNZ);
    unsigned short* C_bf = (unsigned short*)scratch;   // overlays scratch (25.6 < 26.2 MB)
    float* E = (float*)d_out;

    const int gemm_blocks = (N_NODES + 63) / 64;         // 782
    const int row_blocks  = (N_NODES * 64 + 255) / 256;  // 12500
    const int list_blocks = (NNZ + 255) / 256;

    // 0) lists -> CSR (heads contiguous: one fill) + weight transpose
    fill_i32<<<1024, 256, 0, stream>>>(head_a, -1, N_NODES + N_EDGES + N_NODES);
    fill_i32<<<1, 64, 0, stream>>>(cursors, 0, 3);
    build_list<<<list_blocks, 256, 0, stream>>>(adj_rows, head_a, nxt_a, NNZ);
    build_list<<<list_blocks, 256, 0, stream>>>(inc_cols, head_e, nxt_e, NNZ);
    build_list<<<list_blocks, 256, 0, stream>>>(inc_rows, head_n, nxt_n, NNZ);
    pack_csr<<<(N_NODES + 255) / 256, 256, 0, stream>>>(
        head_a, nxt_a, adj_cols, adj_vals, sd_a, col_a, val_a, cursors + 0, N_NODES);
    pack_csr<<<(N_EDGES + 255) / 256, 256, 0, stream>>>(
        head_e, nxt_e, inc_rows, inc_vals, sd_e, node_e, val_e, cursors + 1, N_EDGES);
    pack_csr<<<(N_NODES + 255) / 256, 256, 0, stream>>>(
        head_n, nxt_n, inc_cols, inc_vals, sd_n, edge_n, val_n, cursors + 2, N_NODES);
    cvt_w_transpose<<<256, 256, 0, stream>>>(W00, W01, Wt00, Wt01);

    // 1) B = x @ W01  (bf16, MFMA)
    mfma_gemm<<<gemm_blocks, 256, 0, stream>>>(x, Wt01, AB_bf, N_NODES);

    // 2) F[n] = sum v * sigmoid(D_e)  (double-CSR, registers only)
    edge_gather_csr<<<row_blocks, 256, 0, stream>>>(sd_n, edge_n, val_n,
                                                    sd_e, node_e, val_e,
                                                    AB_bf, F, N_NODES);

    // 3) A = x @ W00  (overwrites B — dead)
    mfma_gemm<<<gemm_blocks, 256, 0, stream>>>(x, Wt00, AB_bf, N_NODES);

    // 4) C = sigmoid(gather_adj(A)) -> bf16  (C_bf overlays dead scratch)
    gather_csr<<<row_blocks, 256, 0, stream>>>(sd_a, col_a, val_a,
                                               AB_bf, C_bf, N_NODES, 1, 1);

    // 5) E = gather_adj(C) -> fp32 in d_out
    gather_csr<<<row_blocks, 256, 0, stream>>>(sd_a, col_a, val_a,
                                               C_bf, E, N_NODES, 0, 0);

    // 6) out = sigmoid(E @ W10 + F @ W11)  (fp32, in-place on d_out)
    final_gemm<<<gemm_blocks, 256, 0, stream>>>(E, F, W10, W11, (float*)d_out, N_NODES);
}

// Round 6
// 1008.867 us; speedup vs baseline: 8.3137x; 1.1220x over previous
//
#include <hip/hip_runtime.h>
#include <math.h>

#define N_NODES 50000
#define N_EDGES 400000
#define CH      256
#define NNZ     800000

typedef short s16x8 __attribute__((ext_vector_type(8)));
typedef float f32x4 __attribute__((ext_vector_type(4)));

__device__ __forceinline__ float sigmoidf_(float x) {
    return 1.0f / (1.0f + __expf(-x));
}
__device__ __forceinline__ unsigned short f2bf(float f) {
    unsigned u = __float_as_uint(f);
    u = (u + 0x7FFFu + ((u >> 16) & 1u)) >> 16;   // RNE
    return (unsigned short)u;
}
__device__ __forceinline__ float bf2f(unsigned short h) {
    return __uint_as_float((unsigned)h << 16);
}

// ---------------------------------------------------------------------------
__global__ __launch_bounds__(256) void fill_i32(int* __restrict__ p, int val, int n)
{
    int stride = gridDim.x * 256;
    for (int i = blockIdx.x * 256 + threadIdx.x; i < n; i += stride) p[i] = val;
}

__global__ __launch_bounds__(256) void build_list(
    const int* __restrict__ key, int* __restrict__ head, int* __restrict__ nxt, int n)
{
    int i = blockIdx.x * 256 + threadIdx.x;
    if (i >= n) return;
    nxt[i] = atomicExch(&head[key[i]], i);
}

// Linked list -> packed CSR (no scan): sd[k] = base | (deg<<20).
__global__ __launch_bounds__(256) void pack_csr(
    const int* __restrict__ head, const int* __restrict__ nxt,
    const int* __restrict__ other, const float* __restrict__ vals_src,
    int* __restrict__ sd, int* __restrict__ col_out, float* __restrict__ val_out,
    int* __restrict__ cursor, int n_keys)
{
    int k = blockIdx.x * 256 + threadIdx.x;
    if (k >= n_keys) return;
    int deg = 0;
    for (int p = head[k]; p >= 0; p = nxt[p]) deg++;
    int base = deg ? atomicAdd(cursor, deg) : 0;
    sd[k] = base | (deg << 20);
    int i = base;
    for (int p = head[k]; p >= 0; p = nxt[p]) {
        col_out[i] = other[p];
        val_out[i] = vals_src[p];
        i++;
    }
}

// W[k][n] fp32 -> Wt[n][k] bf16 (transposed; MFMA B-frags contiguous)
__global__ __launch_bounds__(256) void cvt_w_transpose(
    const float* __restrict__ W0, const float* __restrict__ W1,
    unsigned short* __restrict__ T0, unsigned short* __restrict__ T1)
{
    int n = blockIdx.x, k = threadIdx.x;
    T0[n * 256 + k] = f2bf(W0[k * 256 + n]);
    T1[n * 256 + k] = f2bf(W1[k * 256 + n]);
}

// W[k][n] fp32 -> transposed hi/lo bf16 pair (split-precision GEMM operand)
__global__ __launch_bounds__(256) void cvt_w_hilo(
    const float* __restrict__ W,
    unsigned short* __restrict__ Th, unsigned short* __restrict__ Tl)
{
    int n = blockIdx.x, k = threadIdx.x;
    float w = W[k * 256 + n];
    unsigned short h = f2bf(w);
    Th[n * 256 + k] = h;
    Tl[n * 256 + k] = f2bf(w - bf2f(h));
}

// ---------------------------------------------------------------------------
// MFMA GEMM: Y[M][256] (bf16) = X[M][256] (fp32) @ W (via Wt[n][k] bf16)
// ---------------------------------------------------------------------------
__global__ __launch_bounds__(256) void mfma_gemm(
    const float* __restrict__ X, const unsigned short* __restrict__ Wt,
    unsigned short* __restrict__ Y, int M)
{
    const int wv = threadIdx.x >> 6, lane = threadIdx.x & 63;
    const int row0 = blockIdx.x * 64 + wv * 16;
    const int r = lane & 15, g = lane >> 4;

    f32x4 acc[16];
#pragma unroll
    for (int t = 0; t < 16; t++) acc[t] = (f32x4){0.f, 0.f, 0.f, 0.f};

    int arow = row0 + r; if (arow >= M) arow = M - 1;

#pragma unroll
    for (int k0 = 0; k0 < 256; k0 += 32) {
        const float* xp = X + (size_t)arow * CH + k0 + g * 8;
        float4 f0 = *(const float4*)(xp);
        float4 f1 = *(const float4*)(xp + 4);
        s16x8 a;
        a[0] = f2bf(f0.x); a[1] = f2bf(f0.y); a[2] = f2bf(f0.z); a[3] = f2bf(f0.w);
        a[4] = f2bf(f1.x); a[5] = f2bf(f1.y); a[6] = f2bf(f1.z); a[7] = f2bf(f1.w);
#pragma unroll
        for (int t = 0; t < 16; t++) {
            s16x8 b = *(const s16x8*)(Wt + (size_t)(t * 16 + r) * CH + k0 + g * 8);
            acc[t] = __builtin_amdgcn_mfma_f32_16x16x32_bf16(a, b, acc[t], 0, 0, 0);
        }
    }

    const int drow0 = row0 + g * 4;
#pragma unroll
    for (int t = 0; t < 16; t++) {
        int col = t * 16 + r;
#pragma unroll
        for (int j = 0; j < 4; j++) {
            int dr = drow0 + j;
            if (dr < M) Y[(size_t)dr * CH + col] = f2bf(acc[t][j]);
        }
    }
}

// ---------------------------------------------------------------------------
// CSR gather SpMM (bf16 rows): O[r] = act( sum_i val[i]*S[col[i]] ), unroll x4
// ---------------------------------------------------------------------------
__global__ __launch_bounds__(256) void gather_csr(
    const int* __restrict__ sd, const int* __restrict__ col,
    const float* __restrict__ val, const unsigned short* __restrict__ S,
    void* __restrict__ O, int n_rows, int sig, int out_bf)
{
    int r    = (int)((blockIdx.x * 256u + threadIdx.x) >> 6);
    int lane = threadIdx.x & 63;
    if (r >= n_rows) return;
    r = __builtin_amdgcn_readfirstlane(r);

    unsigned sdv = (unsigned)sd[r];
    int base = (int)(sdv & 0xFFFFFu), deg = (int)(sdv >> 20);
    const int lo = lane * 4;

    float4 acc = make_float4(0.f, 0.f, 0.f, 0.f);
    int i = 0;
    for (; i + 4 <= deg; i += 4) {
        int c0 = col[base+i],   c1 = col[base+i+1];
        int c2 = col[base+i+2], c3 = col[base+i+3];
        float v0 = val[base+i],   v1 = val[base+i+1];
        float v2 = val[base+i+2], v3 = val[base+i+3];
        ushort4 s0 = *(const ushort4*)(S + (size_t)c0 * CH + lo);
        ushort4 s1 = *(const ushort4*)(S + (size_t)c1 * CH + lo);
        ushort4 s2 = *(const ushort4*)(S + (size_t)c2 * CH + lo);
        ushort4 s3 = *(const ushort4*)(S + (size_t)c3 * CH + lo);
        acc.x += v0*bf2f(s0.x) + v1*bf2f(s1.x) + v2*bf2f(s2.x) + v3*bf2f(s3.x);
        acc.y += v0*bf2f(s0.y) + v1*bf2f(s1.y) + v2*bf2f(s2.y) + v3*bf2f(s3.y);
        acc.z += v0*bf2f(s0.z) + v1*bf2f(s1.z) + v2*bf2f(s2.z) + v3*bf2f(s3.z);
        acc.w += v0*bf2f(s0.w) + v1*bf2f(s1.w) + v2*bf2f(s2.w) + v3*bf2f(s3.w);
    }
    for (; i < deg; i++) {
        int   c = col[base+i];
        float v = val[base+i];
        ushort4 s = *(const ushort4*)(S + (size_t)c * CH + lo);
        acc.x = fmaf(v, bf2f(s.x), acc.x);
        acc.y = fmaf(v, bf2f(s.y), acc.y);
        acc.z = fmaf(v, bf2f(s.z), acc.z);
        acc.w = fmaf(v, bf2f(s.w), acc.w);
    }
    if (sig) {
        acc.x = sigmoidf_(acc.x); acc.y = sigmoidf_(acc.y);
        acc.z = sigmoidf_(acc.z); acc.w = sigmoidf_(acc.w);
    }
    if (out_bf) {
        ushort4 o; o.x = f2bf(acc.x); o.y = f2bf(acc.y); o.z = f2bf(acc.z); o.w = f2bf(acc.w);
        *(ushort4*)((unsigned short*)O + (size_t)r * CH + lo) = o;
    } else {
        *(float4*)((float*)O + (size_t)r * CH + lo) = acc;
    }
}

// ---------------------------------------------------------------------------
// Edge branch via double CSR (no atomics, no edge buffer)
// ---------------------------------------------------------------------------
__global__ __launch_bounds__(256) void edge_gather_csr(
    const int* __restrict__ sd_n, const int* __restrict__ edge_n,
    const float* __restrict__ val_n,
    const int* __restrict__ sd_e, const int* __restrict__ node_e,
    const float* __restrict__ val_e,
    const unsigned short* __restrict__ B, float* __restrict__ F, int n_nodes)
{
    int n    = (int)((blockIdx.x * 256u + threadIdx.x) >> 6);
    int lane = threadIdx.x & 63;
    if (n >= n_nodes) return;
    n = __builtin_amdgcn_readfirstlane(n);

    unsigned sdn = (unsigned)sd_n[n];
    int baseN = (int)(sdn & 0xFFFFFu), degN = (int)(sdn >> 20);
    const int lo = lane * 4;

    float4 acc = make_float4(0.f, 0.f, 0.f, 0.f);
    for (int i = 0; i < degN; i++) {
        int   e = edge_n[baseN + i];
        float v = val_n[baseN + i];
        unsigned sde = (unsigned)sd_e[e];
        int baseE = (int)(sde & 0xFFFFFu), degE = (int)(sde >> 20);

        float4 d = make_float4(0.f, 0.f, 0.f, 0.f);
        int j = 0;
        for (; j + 2 <= degE; j += 2) {
            int   m0 = node_e[baseE+j],   m1 = node_e[baseE+j+1];
            float u0 = val_e[baseE+j],    u1 = val_e[baseE+j+1];
            ushort4 b0 = *(const ushort4*)(B + (size_t)m0 * CH + lo);
            ushort4 b1 = *(const ushort4*)(B + (size_t)m1 * CH + lo);
            d.x += u0*bf2f(b0.x) + u1*bf2f(b1.x);
            d.y += u0*bf2f(b0.y) + u1*bf2f(b1.y);
            d.z += u0*bf2f(b0.z) + u1*bf2f(b1.z);
            d.w += u0*bf2f(b0.w) + u1*bf2f(b1.w);
        }
        for (; j < degE; j++) {
            int   m = node_e[baseE+j];
            float u = val_e[baseE+j];
            ushort4 b = *(const ushort4*)(B + (size_t)m * CH + lo);
            d.x = fmaf(u, bf2f(b.x), d.x);
            d.y = fmaf(u, bf2f(b.y), d.y);
            d.z = fmaf(u, bf2f(b.z), d.z);
            d.w = fmaf(u, bf2f(b.w), d.w);
        }
        acc.x = fmaf(v, sigmoidf_(d.x), acc.x);
        acc.y = fmaf(v, sigmoidf_(d.y), acc.y);
        acc.z = fmaf(v, sigmoidf_(d.z), acc.z);
        acc.w = fmaf(v, sigmoidf_(d.w), acc.w);
    }
    *(float4*)(F + (size_t)n * CH + lo) = acc;
}

// ---------------------------------------------------------------------------
// Final GEMM, split-bf16 MFMA, fp32-equivalent:
//   out = sigmoid( E@W10 + F@W11 ),  E fp32 (in d_out, in-place safe), F fp32.
// Each fp32 operand row split in-register: v = hi + lo (bf16 RNE pair).
// acc += Eh@Wh + El@Wh + Eh@Wl  (+ F terms); lo*lo dropped (~1e-5).
// 4 waves/block, wave = 32 rows (two 16-row groups share B-frags), block = 128.
// ---------------------------------------------------------------------------
__device__ __forceinline__ void split8(float4 a, float4 b, s16x8& hi, s16x8& lo)
{
    float v[8] = {a.x, a.y, a.z, a.w, b.x, b.y, b.z, b.w};
#pragma unroll
    for (int i = 0; i < 8; i++) {
        unsigned short h = f2bf(v[i]);
        hi[i] = (short)h;
        lo[i] = (short)f2bf(v[i] - bf2f(h));
    }
}

__global__ __launch_bounds__(256) void final_mfma(
    const float* __restrict__ E, const float* __restrict__ F,
    const unsigned short* __restrict__ Wh10, const unsigned short* __restrict__ Wl10,
    const unsigned short* __restrict__ Wh11, const unsigned short* __restrict__ Wl11,
    float* __restrict__ Y, int M)
{
    const int wv = threadIdx.x >> 6, lane = threadIdx.x & 63;
    const int row0 = blockIdx.x * 128 + wv * 32;
    const int r = lane & 15, g = lane >> 4;

    f32x4 acc[2][16];
#pragma unroll
    for (int gr = 0; gr < 2; gr++)
#pragma unroll
        for (int t = 0; t < 16; t++) acc[gr][t] = (f32x4){0.f, 0.f, 0.f, 0.f};

    int ar0 = row0 + r;      if (ar0 >= M) ar0 = M - 1;
    int ar1 = row0 + 16 + r; if (ar1 >= M) ar1 = M - 1;

    for (int k0 = 0; k0 < 256; k0 += 32) {
        s16x8 eh0, el0, eh1, el1, fh0, fl0, fh1, fl1;
        {
            const float* p = E + (size_t)ar0 * CH + k0 + g * 8;
            split8(*(const float4*)p, *(const float4*)(p + 4), eh0, el0);
            p = E + (size_t)ar1 * CH + k0 + g * 8;
            split8(*(const float4*)p, *(const float4*)(p + 4), eh1, el1);
            p = F + (size_t)ar0 * CH + k0 + g * 8;
            split8(*(const float4*)p, *(const float4*)(p + 4), fh0, fl0);
            p = F + (size_t)ar1 * CH + k0 + g * 8;
            split8(*(const float4*)p, *(const float4*)(p + 4), fh1, fl1);
        }
#pragma unroll
        for (int t = 0; t < 16; t++) {
            size_t wo = (size_t)(t * 16 + r) * CH + k0 + g * 8;
            s16x8 bh0 = *(const s16x8*)(Wh10 + wo);
            s16x8 bl0 = *(const s16x8*)(Wl10 + wo);
            s16x8 bh1 = *(const s16x8*)(Wh11 + wo);
            s16x8 bl1 = *(const s16x8*)(Wl11 + wo);

            acc[0][t] = __builtin_amdgcn_mfma_f32_16x16x32_bf16(eh0, bh0, acc[0][t], 0, 0, 0);
            acc[0][t] = __builtin_amdgcn_mfma_f32_16x16x32_bf16(el0, bh0, acc[0][t], 0, 0, 0);
            acc[0][t] = __builtin_amdgcn_mfma_f32_16x16x32_bf16(eh0, bl0, acc[0][t], 0, 0, 0);
            acc[0][t] = __builtin_amdgcn_mfma_f32_16x16x32_bf16(fh0, bh1, acc[0][t], 0, 0, 0);
            acc[0][t] = __builtin_amdgcn_mfma_f32_16x16x32_bf16(fl0, bh1, acc[0][t], 0, 0, 0);
            acc[0][t] = __builtin_amdgcn_mfma_f32_16x16x32_bf16(fh0, bl1, acc[0][t], 0, 0, 0);

            acc[1][t] = __builtin_amdgcn_mfma_f32_16x16x32_bf16(eh1, bh0, acc[1][t], 0, 0, 0);
            acc[1][t] = __builtin_amdgcn_mfma_f32_16x16x32_bf16(el1, bh0, acc[1][t], 0, 0, 0);
            acc[1][t] = __builtin_amdgcn_mfma_f32_16x16x32_bf16(eh1, bl0, acc[1][t], 0, 0, 0);
            acc[1][t] = __builtin_amdgcn_mfma_f32_16x16x32_bf16(fh1, bh1, acc[1][t], 0, 0, 0);
            acc[1][t] = __builtin_amdgcn_mfma_f32_16x16x32_bf16(fl1, bh1, acc[1][t], 0, 0, 0);
            acc[1][t] = __builtin_amdgcn_mfma_f32_16x16x32_bf16(fh1, bl1, acc[1][t], 0, 0, 0);
        }
    }

#pragma unroll
    for (int gr = 0; gr < 2; gr++) {
        const int drow0 = row0 + gr * 16 + g * 4;
#pragma unroll
        for (int t = 0; t < 16; t++) {
            int col = t * 16 + r;
#pragma unroll
            for (int j = 0; j < 4; j++) {
                int dr = drow0 + j;
                if (dr < M) Y[(size_t)dr * CH + col] = sigmoidf_(acc[gr][t][j]);
            }
        }
    }
}

// ---------------------------------------------------------------------------
extern "C" void kernel_launch(void* const* d_in, const int* in_sizes, int n_in,
                              void* d_out, int out_size, void* d_ws, size_t ws_size,
                              hipStream_t stream)
{
    const float* x        = (const float*)d_in[0];
    const int*   adj_rows = (const int*)  d_in[1];
    const int*   adj_cols = (const int*)  d_in[2];
    const float* adj_vals = (const float*)d_in[3];
    const int*   inc_rows = (const int*)  d_in[4];
    const int*   inc_cols = (const int*)  d_in[5];
    const float* inc_vals = (const float*)d_in[6];
    const float* W00      = (const float*)d_in[7];
    const float* W01      = (const float*)d_in[8];
    const float* W10      = (const float*)d_in[9];
    const float* W11      = (const float*)d_in[10];

    // -------- workspace layout (110.4 MB total; proven-safe < 114.26 MB) ----
    const size_t SZ_AB = (size_t)N_NODES * CH * 2;    // 25.6 MB
    const size_t SZ_F  = (size_t)N_NODES * CH * 4;    // 51.2 MB
    char* ws = (char*)d_ws;
    size_t off = 0;
    unsigned short* AB_bf = (unsigned short*)(ws + off); off += SZ_AB;
    float*          F     = (float*)(ws + off);          off += SZ_F;
    int*   sd_a  = (int*)(ws + off);  off += (size_t)N_NODES * 4;
    int*   col_a = (int*)(ws + off);  off += (size_t)NNZ * 4;
    float* val_a = (float*)(ws + off); off += (size_t)NNZ * 4;
    int*   cursors = (int*)(ws + off); off += 256;
    unsigned short* Wt00  = (unsigned short*)(ws + off); off += (size_t)CH * CH * 2;
    unsigned short* Wt01  = (unsigned short*)(ws + off); off += (size_t)CH * CH * 2;
    unsigned short* Wh10  = (unsigned short*)(ws + off); off += (size_t)CH * CH * 2;
    unsigned short* Wl10  = (unsigned short*)(ws + off); off += (size_t)CH * CH * 2;
    unsigned short* Wh11  = (unsigned short*)(ws + off); off += (size_t)CH * CH * 2;
    unsigned short* Wl11  = (unsigned short*)(ws + off); off += (size_t)CH * CH * 2;
    // scratch: lists + inc CSRs (dead after edge_gather_csr); C_bf overlays it
    char* scratch = ws + off;
    int*   head_a = (int*)(scratch);
    int*   head_e = head_a + N_NODES;
    int*   head_n = head_e + N_EDGES;
    int*   nxt_a  = head_n + N_NODES;
    int*   nxt_e  = nxt_a + NNZ;
    int*   nxt_n  = nxt_e + NNZ;
    int*   sd_n   = nxt_n + NNZ;
    int*   edge_n = sd_n + N_NODES;
    float* val_n  = (float*)(edge_n + NNZ);
    int*   sd_e   = (int*)(val_n + NNZ);
    int*   node_e = sd_e + N_EDGES;
    float* val_e  = (float*)(node_e + NNZ);
    unsigned short* C_bf = (unsigned short*)scratch;
    float* E = (float*)d_out;

    const int gemm_blocks  = (N_NODES + 63) / 64;          // 782
    const int final_blocks = (N_NODES + 127) / 128;        // 391
    const int row_blocks   = (N_NODES * 64 + 255) / 256;   // 12500
    const int list_blocks  = (NNZ + 255) / 256;

    // 0) lists -> CSR + weight transposes (incl. hi/lo split for W10/W11)
    fill_i32<<<1024, 256, 0, stream>>>(head_a, -1, N_NODES + N_EDGES + N_NODES);
    fill_i32<<<1, 64, 0, stream>>>(cursors, 0, 3);
    build_list<<<list_blocks, 256, 0, stream>>>(adj_rows, head_a, nxt_a, NNZ);
    build_list<<<list_blocks, 256, 0, stream>>>(inc_cols, head_e, nxt_e, NNZ);
    build_list<<<list_blocks, 256, 0, stream>>>(inc_rows, head_n, nxt_n, NNZ);
    pack_csr<<<(N_NODES + 255) / 256, 256, 0, stream>>>(
        head_a, nxt_a, adj_cols, adj_vals, sd_a, col_a, val_a, cursors + 0, N_NODES);
    pack_csr<<<(N_EDGES + 255) / 256, 256, 0, stream>>>(
        head_e, nxt_e, inc_rows, inc_vals, sd_e, node_e, val_e, cursors + 1, N_EDGES);
    pack_csr<<<(N_NODES + 255) / 256, 256, 0, stream>>>(
        head_n, nxt_n, inc_cols, inc_vals, sd_n, edge_n, val_n, cursors + 2, N_NODES);
    cvt_w_transpose<<<256, 256, 0, stream>>>(W00, W01, Wt00, Wt01);
    cvt_w_hilo<<<256, 256, 0, stream>>>(W10, Wh10, Wl10);
    cvt_w_hilo<<<256, 256, 0, stream>>>(W11, Wh11, Wl11);

    // 1) B = x @ W01  (bf16, MFMA)
    mfma_gemm<<<gemm_blocks, 256, 0, stream>>>(x, Wt01, AB_bf, N_NODES);

    // 2) F[n] = sum v * sigmoid(D_e)  (double-CSR, registers only)
    edge_gather_csr<<<row_blocks, 256, 0, stream>>>(sd_n, edge_n, val_n,
                                                    sd_e, node_e, val_e,
                                                    AB_bf, F, N_NODES);

    // 3) A = x @ W00  (overwrites B — dead)
    mfma_gemm<<<gemm_blocks, 256, 0, stream>>>(x, Wt00, AB_bf, N_NODES);

    // 4) C = sigmoid(gather_adj(A)) -> bf16  (overlays dead scratch)
    gather_csr<<<row_blocks, 256, 0, stream>>>(sd_a, col_a, val_a,
                                               AB_bf, C_bf, N_NODES, 1, 1);

    // 5) E = gather_adj(C) -> fp32 in d_out
    gather_csr<<<row_blocks, 256, 0, stream>>>(sd_a, col_a, val_a,
                                               C_bf, E, N_NODES, 0, 0);

    // 6) out = sigmoid(E @ W10 + F @ W11)  (split-bf16 MFMA, fp32-equivalent,
    //    in-place on d_out: each block reads only its own rows pre-write)
    final_mfma<<<final_blocks, 256, 0, stream>>>(E, F, Wh10, Wl10, Wh11, Wl11,
                                                 (float*)d_out, N_NODES);
}